// Round 7
// baseline (3258.068 us; speedup 1.0000x reference)
//
#include <hip/hip_runtime.h>
#include <math.h>

#define NC1 150
#define HW 196          // 14*14
#define CST 153         // LDS row stride: odd -> conflict-free scalar ds access
#define NTOTF (HW*CST)  // 29988
#define NB 1024
#define DD 32
#define NHD 4
#define HDIM 8
#define KG 2352         // ceil(0.08 * 150*14*14)
#define KCH 10

// ---------------- K0: 2D sinusoidal positional embedding [196,32] ----------------
__global__ void pos2d_kernel(float* __restrict__ pos) {
  int i = blockIdx.x * 256 + threadIdx.x;
  if (i >= HW * DD) return;
  int s = i >> 5, d = i & 31;
  int h = s / 14, w = s % 14;
  int p = (d < 16) ? h : w;
  int dd = (d < 16) ? d : d - 16;
  int j = dd >> 1;
  float dv = expf(-(logf(10000.0f) / 16.0f) * (float)(2 * j));
  float ang = (float)p * dv;
  pos[i] = (dd & 1) ? cosf(ang) : sinf(ang);
}

// extract window elements [K0,K1) of the 84-slot (9x9 + 3 pad) patch into xr[0..K1-K0)
template<int K0, int K1>
__device__ __forceinline__ void extract_win(const float* __restrict__ xs, int h, int w,
                                            float* __restrict__ xr) {
#pragma unroll
  for (int k = K0; k < K1; ++k) {
    if (k < 81) {
      int i = k / 9, j = k % 9;
      int r = 2 * h - 4 + i, cl = 2 * w - 4 + j;
      xr[k - K0] = (r >= 0 && r < 28 && cl >= 0 && cl < 28) ? xs[r * 28 + cl] : 0.f;
    } else {
      xr[k - K0] = 0.f;
    }
  }
}

// accumulate NCH channels over weight quads [KQ0,KQ1); xr holds elements 4*KQ0..4*KQ1
template<int NCH, int KQ0, int KQ1>
__device__ __forceinline__ void conv_acc(const float* __restrict__ wp,
                                         const float* __restrict__ xr,
                                         float* __restrict__ acc) {
#pragma unroll
  for (int pr = 0; pr < NCH / 2; ++pr) {
    const float* w0 = wp + (2 * pr + 0) * 84;
    const float* w1 = wp + (2 * pr + 1) * 84;
#pragma unroll
    for (int kq = KQ0; kq < KQ1; ++kq) {
      float4 a0 = *(const float4*)(w0 + kq * 4);
      float4 a1 = *(const float4*)(w1 + kq * 4);
      int kb = (kq - KQ0) * 4;
      acc[2 * pr + 0] += xr[kb + 0] * a0.x;
      acc[2 * pr + 0] += xr[kb + 1] * a0.y;
      acc[2 * pr + 0] += xr[kb + 2] * a0.z;
      acc[2 * pr + 0] += xr[kb + 3] * a0.w;
      acc[2 * pr + 1] += xr[kb + 0] * a1.x;
      acc[2 * pr + 1] += xr[kb + 1] * a1.y;
      acc[2 * pr + 1] += xr[kb + 2] * a1.z;
      acc[2 * pr + 1] += xr[kb + 3] * a1.w;
    }
  }
}

// ---------------- K1 (fused): conv -> register-radix kth -> top-10+embed+PE ----------
// R7: radix-select passes scan the conv values held in REGISTERS (each active thread
// owns exactly 30 channels: 16 from phase0 c=[0,80), 14 from phase1 c=[80,150)) —
// zero LDS sweeps (was 3 full 120KB sweeps, ~75us/block of LDS-pipe time). Suffix
// scan via wave shfl (no LDS scan barriers). s_krem/s_prefix snapshotted before the
// build barrier (fixes read/write race). Zero-skip exactness unchanged.
__global__ __launch_bounds__(1024, 4) void fused_kernel(const float* __restrict__ x,
                                                        const float* __restrict__ cw,
                                                        const float* __restrict__ CE,
                                                        const float* __restrict__ pos,
                                                        float* __restrict__ seqo) {
  __shared__ alignas(16) float As[NTOTF];     // 119952 B
  __shared__ alignas(16) float wl[80 * 84];   // 26880 B (reused as CE[150][33] later)
  __shared__ alignas(16) float xs[784];       // 3136 B
  __shared__ unsigned hist[2048];             // 8192 B
  __shared__ unsigned wsum[4];
  __shared__ unsigned s_prefix, s_krem, s_max;   // total ~158.2 KB

  int b = blockIdx.x, tid = threadIdx.x;
  int lane = tid & 63, wid = tid >> 6;

  if (tid < 196) ((float4*)xs)[tid] = ((const float4*)(x + (size_t)b * 784))[tid];
  if (tid == 0) { s_prefix = 0u; s_krem = KG; s_max = 0u; }
  __syncthreads();

  int strip = tid / 196;            // 0..4 active
  int s = tid - strip * 196;
  bool act = (tid < 980);
  int h = s / 14, w = s % 14;
  float* Asr = As + s * CST;

  float a_r[30];
#pragma unroll
  for (int q = 0; q < 30; ++q) a_r[q] = 0.f;

  // ---- conv phase 0: channels [0,80), strip owns 16 ----
  for (int i = tid; i < 80 * 84; i += 1024) {
    int rr = i / 84, k = i - rr * 84;
    wl[i] = (k < 81) ? cw[rr * 81 + k] : 0.f;
  }
  __syncthreads();
  if (act) {
    const float* wp = wl + strip * 16 * 84;
    float acc[16];
#pragma unroll
    for (int q = 0; q < 16; ++q) acc[q] = 0.f;
    {
      float xl[48]; extract_win<0, 48>(xs, h, w, xl);
      conv_acc<16, 0, 12>(wp, xl, acc);
    }
    {
      float xh[36]; extract_win<48, 84>(xs, h, w, xh);
      conv_acc<16, 12, 21>(wp, xh, acc);
    }
    int cbase = strip * 16;
#pragma unroll
    for (int q = 0; q < 16; ++q) {
      float v = fmaxf(acc[q], 0.f);
      a_r[q] = v;
      Asr[cbase + q] = v;
    }
  }
  __syncthreads();                  // ph0 wl reads done
  // ---- conv phase 1: channels [80,150), strip owns 14 ----
  for (int i = tid; i < 70 * 84; i += 1024) {
    int rr = i / 84, k = i - rr * 84;
    wl[i] = (k < 81) ? cw[(80 + rr) * 81 + k] : 0.f;
  }
  __syncthreads();
  if (act) {
    const float* wp = wl + strip * 14 * 84;
    float acc[14];
#pragma unroll
    for (int q = 0; q < 14; ++q) acc[q] = 0.f;
    {
      float xl[48]; extract_win<0, 48>(xs, h, w, xl);
      conv_acc<14, 0, 12>(wp, xl, acc);
    }
    {
      float xh[36]; extract_win<48, 84>(xs, h, w, xh);
      conv_acc<14, 12, 21>(wp, xh, acc);
    }
    int cbase = 80 + strip * 14;
#pragma unroll
    for (int q = 0; q < 14; ++q) {
      float v = fmaxf(acc[q], 0.f);
      a_r[16 + q] = v;
      Asr[cbase + q] = v;
    }
  }
  if (tid < 196) { float* p = As + tid * CST; p[150] = 0.f; p[151] = 0.f; p[152] = 0.f; }
  __syncthreads();                  // ph1 wl reads + As writes done

  // ---- stage CE into dead wl region (padded to 33/row) ----
  float* CEs = wl;
  for (int i = tid; i < NC1 * 32; i += 1024) {
    int c = i >> 5, e = i & 31;
    CEs[c * 33 + e] = CE[i];
  }
  // ---- per-sample max: register -> wave shfl -> 1 atomic/wave ----
  {
    float vm = 0.f;
#pragma unroll
    for (int q = 0; q < 30; ++q) vm = fmaxf(vm, a_r[q]);
    unsigned um = __float_as_uint(vm);   // non-neg floats: bit order == float order
#pragma unroll
    for (int off = 32; off >= 1; off >>= 1) um = max(um, (unsigned)__shfl_xor((int)um, off));
    if (lane == 0) atomicMax(&s_max, um);
  }

  // ---- kth: 3-pass radix select, values scanned from REGISTERS ----
  for (int pass = 0; pass < 3; ++pass) {
    hist[tid & 2047] = 0u;   // 1024 threads x2... need full clear:
    hist[1024 + tid] = (tid < 1024) ? 0u : hist[1024 + tid];
    __syncthreads();
    int shift = (pass == 0) ? 21 : (pass == 1 ? 10 : 0);
    int bits = (pass == 2) ? 10 : 11;
    unsigned mask = (1u << bits) - 1u;
    unsigned pfx = s_prefix;          // snapshot BEFORE build barrier (no race)
    unsigned krem = s_krem;
    int hishift = shift + bits;
    if (pass == 0) {
#pragma unroll
      for (int q = 0; q < 30; ++q) {
        unsigned u = __float_as_uint(a_r[q]);
        if (u) atomicAdd(&hist[u >> 21], 1u);
      }
    } else {
#pragma unroll
      for (int q = 0; q < 30; ++q) {
        unsigned u = __float_as_uint(a_r[q]);
        if (u && (u >> hishift) == pfx) atomicAdd(&hist[(u >> shift) & mask], 1u);
      }
    }
    __syncthreads();
    int segsz = (1 << bits) >> 8;     // 8 or 4
    unsigned segv = 0u, sufv = 0u;
    if (tid < 256) {
      for (int j = 0; j < segsz; ++j) segv += hist[tid * segsz + j];
      sufv = segv;
#pragma unroll
      for (int st = 1; st < 64; st <<= 1) {
        unsigned o = (unsigned)__shfl_down((int)sufv, st);
        if (lane + st < 64) sufv += o;
      }
      if (lane == 0) wsum[wid] = sufv;   // wave total (suffix at lane 0)
    }
    __syncthreads();
    if (tid < 256) {
      unsigned tail = 0u;
      for (int ww = wid + 1; ww < 4; ++ww) tail += wsum[ww];
      sufv += tail;                      // total count in segments >= tid
      unsigned above = sufv - segv;      // count strictly above this segment
      if (above < krem && sufv >= krem) {   // at most one winner
        unsigned cum = above;
        int dsel = tid * segsz;
        for (int d2 = segsz - 1; d2 >= 0; --d2) {
          int dd = tid * segsz + d2;
          if (cum + hist[dd] >= krem) { dsel = dd; break; }
          cum += hist[dd];
        }
        s_prefix = (pfx << bits) | (unsigned)dsel;
        s_krem = krem - cum;
      }
    }
    __syncthreads();
  }

  // ---- seq: thread-per-location streaming top-10 + CE embed + PE ----
  float T = __uint_as_float(s_prefix);
  float gm = __uint_as_float(s_max);
  float gi = (gm == 0.0f) ? 0.0f : 1.0f / gm;
  if (tid < 196) {
    const float* row = As + tid * CST;
    float tv[KCH]; int tc[KCH];
#pragma unroll
    for (int k = 0; k < KCH; ++k) { tv[k] = -1.0f; tc[k] = 0; }
    for (int c = 0; c < NC1; ++c) {
      float v = row[c];
      v = (v >= T) ? v : 0.0f;
      if (v > tv[KCH - 1]) {              // stable: earlier c wins ties
        float iv = v; int ic = c;
#pragma unroll
        for (int j = 0; j < KCH; ++j) {
          bool gt = iv > tv[j];
          float nv = gt ? iv : tv[j]; int nc = gt ? ic : tc[j];
          float ov = gt ? tv[j] : iv; int oc = gt ? tc[j] : ic;
          tv[j] = nv; tc[j] = nc; iv = ov; ic = oc;
        }
      }
    }
    float acc[32];
#pragma unroll
    for (int e = 0; e < 32; ++e) acc[e] = 0.f;
#pragma unroll
    for (int k = 0; k < KCH; ++k) {
      float v = tv[k];
      const float* cr = CEs + tc[k] * 33;
#pragma unroll
      for (int e = 0; e < 32; ++e) acc[e] += v * cr[e];
    }
    float* op = seqo + ((size_t)b * HW + tid) * DD;
    const float* pr = pos + tid * DD;
#pragma unroll
    for (int e4 = 0; e4 < 8; ++e4) {
      float4 pv = ((const float4*)pr)[e4];
      float4 o;
      o.x = acc[e4 * 4 + 0] * gi + pv.x;
      o.y = acc[e4 * 4 + 1] * gi + pv.y;
      o.z = acc[e4 * 4 + 2] * gi + pv.z;
      o.w = acc[e4 * 4 + 3] * gi + pv.w;
      ((float4*)op)[e4] = o;
    }
  }
}

// ---------------- K4: one-layer MHA, single-pass softmax w/ Cauchy-Schwarz shift ----
__global__ __launch_bounds__(256) void attn_kernel(const float* __restrict__ seq,
                                                   const float* __restrict__ Wqkv,
                                                   const float* __restrict__ bqkv,
                                                   float* __restrict__ ctxo) {
  __shared__ float sq[HW * HDIM], sk[HW * HDIM], sv[HW * HDIM];
  __shared__ float swq[24 * DD];
  __shared__ float sbq[24];
  __shared__ unsigned s_kk;
  int blk = blockIdx.x;
  int b = blk >> 2, h = blk & 3;
  int tid = threadIdx.x;
  for (int i = tid; i < 24 * DD; i += 256) {
    int r = i >> 5, e = i & 31;
    int grow = (r >> 3) * DD + h * HDIM + (r & 7);
    swq[i] = Wqkv[grow * DD + e];
  }
  if (tid < 24) sbq[tid] = bqkv[(tid >> 3) * DD + h * HDIM + (tid & 7)];
  if (tid == 0) s_kk = 0u;
  __syncthreads();
  if (tid < HW) {
    int s = tid;
    const float* row = seq + ((size_t)b * HW + s) * DD;
    float xr[32];
#pragma unroll
    for (int e = 0; e < 8; ++e) {
      float4 f = ((const float4*)row)[e];
      xr[e * 4 + 0] = f.x; xr[e * 4 + 1] = f.y; xr[e * 4 + 2] = f.z; xr[e * 4 + 3] = f.w;
    }
    float kk = 0.f;
#pragma unroll
    for (int r = 0; r < 24; ++r) {
      const float* wr = swq + r * DD;
      float acc = sbq[r];
#pragma unroll
      for (int e = 0; e < DD; e += 4) {
        float4 wv = *(const float4*)(wr + e);
        acc += xr[e + 0] * wv.x + xr[e + 1] * wv.y + xr[e + 2] * wv.z + xr[e + 3] * wv.w;
      }
      int which = r >> 3, d = r & 7;
      if (which == 0) sq[s * HDIM + d] = acc;
      else if (which == 1) { sk[s * HDIM + d] = acc; kk += acc * acc; }
      else sv[s * HDIM + d] = acc;
    }
    atomicMax(&s_kk, __float_as_uint(kk));
  }
  __syncthreads();
  if (tid >= HW) return;
  int qr = tid;
  float qreg[HDIM];
  float qq = 0.f;
#pragma unroll
  for (int d = 0; d < HDIM; ++d) { qreg[d] = sq[qr * HDIM + d]; qq += qreg[d] * qreg[d]; }
  const float scale = 0.3535533905932738f;
  float kkmax = __uint_as_float(s_kk);
  float negM = -sqrtf(qq * kkmax) * scale;
  float l = 0.f, ctx[HDIM];
#pragma unroll
  for (int d = 0; d < HDIM; ++d) ctx[d] = 0.f;
#pragma unroll 2
  for (int t = 0; t < HW; ++t) {
    const float* kr = sk + t * HDIM;
    float sc = 0.f;
#pragma unroll
    for (int d = 0; d < HDIM; ++d) sc += qreg[d] * kr[d];
    float p = __expf(fmaf(sc, scale, negM));
    l += p;
    const float* vr = sv + t * HDIM;
#pragma unroll
    for (int d = 0; d < HDIM; ++d) ctx[d] += p * vr[d];
  }
  float inv = 1.0f / l;
  float* op = ctxo + ((size_t)b * HW + qr) * DD + h * HDIM;
  float4 o0, o1;
  o0.x = ctx[0] * inv; o0.y = ctx[1] * inv; o0.z = ctx[2] * inv; o0.w = ctx[3] * inv;
  o1.x = ctx[4] * inv; o1.y = ctx[5] * inv; o1.z = ctx[6] * inv; o1.w = ctx[7] * inv;
  ((float4*)op)[0] = o0; ((float4*)op)[1] = o1;
}

// ---------------- K5: out projection [N,32] x [32,32]^T + b ----------------
__global__ __launch_bounds__(256) void outproj_kernel(const float* __restrict__ ctx,
                                                      const float* __restrict__ Wo,
                                                      const float* __restrict__ bo,
                                                      float* __restrict__ out) {
  __shared__ float sw[32 * 32];
  __shared__ float sb2[32];
  int tid = threadIdx.x;
  for (int i = tid; i < 1024; i += 256) sw[i] = Wo[i];
  if (tid < 32) sb2[tid] = bo[tid];
  __syncthreads();
  int gid = blockIdx.x * 256 + tid;
  int row = gid >> 3, d4 = gid & 7;
  if (row >= NB * HW) return;
  const float* cr = ctx + (size_t)row * 32;
  float xr[32];
#pragma unroll
  for (int e = 0; e < 8; ++e) {
    float4 f = ((const float4*)cr)[e];
    xr[e * 4 + 0] = f.x; xr[e * 4 + 1] = f.y; xr[e * 4 + 2] = f.z; xr[e * 4 + 3] = f.w;
  }
  float4 o;
  float* oo = (float*)&o;
#pragma unroll
  for (int q = 0; q < 4; ++q) {
    int d = d4 * 4 + q;
    float acc = sb2[d];
#pragma unroll
    for (int e = 0; e < 32; ++e) acc += xr[e] * sw[d * 32 + e];
    oo[q] = acc;
  }
  *(float4*)(out + (size_t)row * 32 + d4 * 4) = o;
}

extern "C" void kernel_launch(void* const* d_in, const int* in_sizes, int n_in,
                              void* d_out, int out_size, void* d_ws, size_t ws_size,
                              hipStream_t stream) {
  const float* x  = (const float*)d_in[0];
  const float* cw = (const float*)d_in[1];
  const float* ce = (const float*)d_in[2];
  const float* wq = (const float*)d_in[3];
  const float* bq = (const float*)d_in[4];
  const float* wo = (const float*)d_in[5];
  const float* bo = (const float*)d_in[6];
  float* out = (float*)d_out;
  float* ws  = (float*)d_ws;

  // ws layout (floats): ctx [NB*HW*DD] | pos [196*32]
  float* ctx = ws;
  float* pos = ws + (size_t)NB * HW * DD;

  pos2d_kernel<<<(HW * DD + 255) / 256, 256, 0, stream>>>(pos);
  fused_kernel<<<NB, 1024, 0, stream>>>(x, cw, ce, pos, out);   // seq -> d_out
  attn_kernel<<<NB * NHD, 256, 0, stream>>>(out, wq, bq, ctx);  // ctx -> ws
  outproj_kernel<<<(NB * HW * 8) / 256, 256, 0, stream>>>(ctx, wo, bo, out);
}